// Round 7
// baseline (936.867 us; speedup 1.0000x reference)
//
#include <hip/hip_runtime.h>
#include <math.h>

#define N_ENT     20000
#define N_RELN    400
#define N_TIME    366
#define N_META    800
#define NE        200000
#define NPE       80000
// dims: ENT=160, REL=160, TIME=80; DIN_E=400, DIN_R=320; NL=6

typedef __attribute__((ext_vector_type(8))) short short8;
typedef __attribute__((ext_vector_type(4))) float f32x4;

static __device__ __forceinline__ ushort f2bf(float x) {
    unsigned u = __float_as_uint(x);
    unsigned r = (u + 0x7FFF + ((u >> 16) & 1)) >> 16;   // RN-to-even
    return (ushort)r;
}
static __device__ __forceinline__ float bf2f(ushort b) {
    return __uint_as_float(((unsigned)b) << 16);
}

// ---------------------------------------------------------------------------
// Weight prep: 18 big 160x160 matrices -> transposed [col][k] bf16 hi/lo.
// ---------------------------------------------------------------------------
struct BPrep { const float* W[18]; };

__global__ __launch_bounds__(256) void bprep(BPrep bp, ushort* __restrict__ hi, ushort* __restrict__ lo)
{
    int idx = blockIdx.x * 256 + threadIdx.x;       // (s, n, kc): 18*160*20
    if (idx >= 18 * 160 * 20) return;
    int s = idx / 3200, rem = idx - s * 3200;
    int n = rem / 20, kc = rem - n * 20;
    const float* __restrict__ W = bp.W[s];
    ushort h[8], l[8];
#pragma unroll
    for (int j = 0; j < 8; ++j) {
        float x = W[(kc * 8 + j) * 160 + n];
        h[j] = f2bf(x);
        l[j] = f2bf(x - bf2f(h[j]));
    }
    size_t o = (size_t)s * 25600 + n * 160 + kc * 8;
    *(short8*)(hi + o) = *(short8*)h;
    *(short8*)(lo + o) = *(short8*)l;
}

// ---------------------------------------------------------------------------
// Stage P1 (packed): role < ns -> register-tiled small GEMM (round-6 body,
// PROVEN); role == ns -> aprep grid-stride over nitems=400000 (round-4 bug
// was nitems=50000 — only 1/8 of the activation split).
// ---------------------------------------------------------------------------
struct SmallDesc {
    const float* A;
    const float* B;
    const float* bias;
    float*       C;
    int M, K, N, ldb, relu;
};
struct SmallBatch { SmallDesc d[18]; };

#define FMA4(acc, a, b) { acc.x = fmaf(a, b.x, acc.x); acc.y = fmaf(a, b.y, acc.y); \
                          acc.z = fmaf(a, b.z, acc.z); acc.w = fmaf(a, b.w, acc.w); }

__global__ __launch_bounds__(256) void stage_p1(SmallBatch sb, int ns,
    const float* __restrict__ ain, ushort* __restrict__ ah, ushort* __restrict__ al, int nitems)
{
    int role = blockIdx.y;
    int tid = blockIdx.x * 256 + threadIdx.x;
    if (role == ns) {
        int stride = gridDim.x * 256;
        for (int i = tid; i < nitems; i += stride) {
            const float* p = ain + (size_t)i * 8;
            ushort h[8], l[8];
#pragma unroll
            for (int j = 0; j < 8; ++j) {
                float x = p[j];
                h[j] = f2bf(x);
                l[j] = f2bf(x - bf2f(h[j]));
            }
            *(short8*)(ah + (size_t)i * 8) = *(short8*)h;
            *(short8*)(al + (size_t)i * 8) = *(short8*)l;
        }
        return;
    }
    SmallDesc dd = sb.d[role];
    int ng = dd.N >> 2;
    int mb = tid / ng;
    int nmb = (dd.M + 3) >> 2;
    if (mb >= nmb) return;
    int g = tid - mb * ng;
    int r0 = mb * 4;
    int mlast = dd.M - 1;
    const float* A0 = dd.A + (size_t)min(r0 + 0, mlast) * dd.K;
    const float* A1 = dd.A + (size_t)min(r0 + 1, mlast) * dd.K;
    const float* A2 = dd.A + (size_t)min(r0 + 2, mlast) * dd.K;
    const float* A3 = dd.A + (size_t)min(r0 + 3, mlast) * dd.K;
    const float* Bp = dd.B + g * 4;
    float4 c0 = {0,0,0,0}, c1 = {0,0,0,0}, c2 = {0,0,0,0}, c3 = {0,0,0,0};
    for (int k = 0; k < dd.K; k += 4) {
        float4 b0 = *(const float4*)(Bp + (size_t)(k + 0) * dd.ldb);
        float4 b1 = *(const float4*)(Bp + (size_t)(k + 1) * dd.ldb);
        float4 b2 = *(const float4*)(Bp + (size_t)(k + 2) * dd.ldb);
        float4 b3 = *(const float4*)(Bp + (size_t)(k + 3) * dd.ldb);
        float4 a0 = *(const float4*)(A0 + k);
        float4 a1 = *(const float4*)(A1 + k);
        float4 a2 = *(const float4*)(A2 + k);
        float4 a3 = *(const float4*)(A3 + k);
        FMA4(c0, a0.x, b0) FMA4(c0, a0.y, b1) FMA4(c0, a0.z, b2) FMA4(c0, a0.w, b3)
        FMA4(c1, a1.x, b0) FMA4(c1, a1.y, b1) FMA4(c1, a1.z, b2) FMA4(c1, a1.w, b3)
        FMA4(c2, a2.x, b0) FMA4(c2, a2.y, b1) FMA4(c2, a2.z, b2) FMA4(c2, a2.w, b3)
        FMA4(c3, a3.x, b0) FMA4(c3, a3.y, b1) FMA4(c3, a3.z, b2) FMA4(c3, a3.w, b3)
    }
    float4 bv = {0,0,0,0};
    if (dd.bias) bv = *(const float4*)(dd.bias + g * 4);
    c0.x += bv.x; c0.y += bv.y; c0.z += bv.z; c0.w += bv.w;
    c1.x += bv.x; c1.y += bv.y; c1.z += bv.z; c1.w += bv.w;
    c2.x += bv.x; c2.y += bv.y; c2.z += bv.z; c2.w += bv.w;
    c3.x += bv.x; c3.y += bv.y; c3.z += bv.z; c3.w += bv.w;
    if (dd.relu) {
        c0.x = fmaxf(c0.x, 0.f); c0.y = fmaxf(c0.y, 0.f); c0.z = fmaxf(c0.z, 0.f); c0.w = fmaxf(c0.w, 0.f);
        c1.x = fmaxf(c1.x, 0.f); c1.y = fmaxf(c1.y, 0.f); c1.z = fmaxf(c1.z, 0.f); c1.w = fmaxf(c1.w, 0.f);
        c2.x = fmaxf(c2.x, 0.f); c2.y = fmaxf(c2.y, 0.f); c2.z = fmaxf(c2.z, 0.f); c2.w = fmaxf(c2.w, 0.f);
        c3.x = fmaxf(c3.x, 0.f); c3.y = fmaxf(c3.y, 0.f); c3.z = fmaxf(c3.z, 0.f); c3.w = fmaxf(c3.w, 0.f);
    }
    float* C = dd.C + (size_t)r0 * dd.N + g * 4;
    if (r0 + 0 < dd.M) *(float4*)(C + 0 * (size_t)dd.N) = c0;
    if (r0 + 1 < dd.M) *(float4*)(C + 1 * (size_t)dd.N) = c1;
    if (r0 + 2 < dd.M) *(float4*)(C + 2 * (size_t)dd.N) = c2;
    if (r0 + 3 < dd.M) *(float4*)(C + 3 * (size_t)dd.N) = c3;
}

// ---------------------------------------------------------------------------
// Stage P2 (packed): roles 0..2 -> MFMA split-bf16 big GEMM (round-3 proven
// body); role 3 -> rel aggregation (6 segments x 40 col-groups, 256 thr).
// LDS: 35.8KB + 3.8KB part = 39.7KB -> 4 blocks/CU.
// ---------------------------------------------------------------------------
struct BigMF {
    const ushort* bh[3];
    const ushort* bl[3];
    const float*  bias[3];
    float*        C[3];
};
struct AggRelA {
    const int* rowptr;
    const int4* pack;
    const float *bmI, *bmO, *brI, *brO;
    float* H;
    int relu;
};

__global__ __launch_bounds__(256, 4) void stage_p2(
    const ushort* __restrict__ Ah, const ushort* __restrict__ Al, int M,
    BigMF bb, AggRelA ar)
{
    __shared__ ushort Ahi[64][40], Alo[64][40];
    __shared__ ushort Bhi[160][40], Blo[160][40];
    __shared__ float part[6][40][4];
    const int role = blockIdx.y;
    const int t = threadIdx.x;

    if (role < 3) {
        const int m0 = blockIdx.x * 64;
        if (m0 >= M) return;
        const ushort* __restrict__ Bh = bb.bh[role];
        const ushort* __restrict__ Bl = bb.bl[role];
        const float*  __restrict__ bias = bb.bias[role];
        float* __restrict__ C = bb.C[role];
        const int lane = t & 63, w = t >> 6;
        const int fr = lane & 15, fq = lane >> 4;

        f32x4 acc[10];
#pragma unroll
        for (int i = 0; i < 10; ++i) acc[i] = (f32x4){0.f, 0.f, 0.f, 0.f};

        for (int k0 = 0; k0 < 160; k0 += 32) {
            {
                int r = t >> 2, kc = t & 3;
                int row = m0 + r;
                short8 vh = {0,0,0,0,0,0,0,0}, vl = {0,0,0,0,0,0,0,0};
                if (row < M) {
                    size_t o = (size_t)row * 160 + k0 + kc * 8;
                    vh = *(const short8*)(Ah + o);
                    vl = *(const short8*)(Al + o);
                }
                *(short8*)&Ahi[r][kc * 8] = vh;
                *(short8*)&Alo[r][kc * 8] = vl;
            }
#pragma unroll
            for (int i = 0; i < 3; ++i) {
                int idx = t + i * 256;
                if (idx < 640) {
                    int col = idx >> 2, kc = idx & 3;
                    size_t o = (size_t)col * 160 + k0 + kc * 8;
                    *(short8*)&Bhi[col][kc * 8] = *(const short8*)(Bh + o);
                    *(short8*)&Blo[col][kc * 8] = *(const short8*)(Bl + o);
                }
            }
            __syncthreads();
            short8 ahv = *(const short8*)&Ahi[w * 16 + fr][fq * 8];
            short8 alv = *(const short8*)&Alo[w * 16 + fr][fq * 8];
#pragma unroll
            for (int tt = 0; tt < 10; ++tt) {
                short8 bh = *(const short8*)&Bhi[tt * 16 + fr][fq * 8];
                short8 bl = *(const short8*)&Blo[tt * 16 + fr][fq * 8];
                acc[tt] = __builtin_amdgcn_mfma_f32_16x16x32_bf16(ahv, bh, acc[tt], 0, 0, 0);
                acc[tt] = __builtin_amdgcn_mfma_f32_16x16x32_bf16(alv, bh, acc[tt], 0, 0, 0);
                acc[tt] = __builtin_amdgcn_mfma_f32_16x16x32_bf16(ahv, bl, acc[tt], 0, 0, 0);
            }
            __syncthreads();
        }
#pragma unroll
        for (int tt = 0; tt < 10; ++tt) {
            int col = tt * 16 + fr;
            float bv = bias ? bias[col] : 0.f;
#pragma unroll
            for (int q = 0; q < 4; ++q) {
                int row = m0 + w * 16 + fq * 4 + q;
                if (row < M) C[(size_t)row * 160 + col] = acc[tt][q] + bv;
            }
        }
        return;
    }

    // role 3: rel aggregation
    int n = blockIdx.x;
    if (n >= N_RELN) return;
    int g = t % 40, s = t / 40;
    int b = ar.rowptr[n], e = ar.rowptr[n + 1];
    if (s < 6) {
        int c = g * 4;
        float ax = 0.f, ay = 0.f, az = 0.f, aw = 0.f;
        for (int j = b + s; j < e; j += 6) {
            int4 p = ar.pack[j];
            const float* pm = (p.w ? ar.bmO : ar.bmI) + (size_t)p.x * 160 + c;
            const float* pr = (p.w ? ar.brO : ar.brI) + (size_t)p.y * 160 + c;
            float4 vm = *(const float4*)pm;
            float4 vr = *(const float4*)pr;
            ax += vm.x + vr.x; ay += vm.y + vr.y;
            az += vm.z + vr.z; aw += vm.w + vr.w;
        }
        part[s][g][0] = ax; part[s][g][1] = ay;
        part[s][g][2] = az; part[s][g][3] = aw;
    }
    __syncthreads();
    if (t < 160) {
        int gg = t >> 2, q = t & 3;
        float acc = 0.f;
#pragma unroll
        for (int s2 = 0; s2 < 6; ++s2) acc += part[s2][gg][q];
        size_t idx = (size_t)n * 160 + t;
        float h = ar.H[idx];
        int d = e - b;
        if (d > 0) h = fmaf(acc, 1.0f / (float)d, h);
        if (ar.relu) h = fmaxf(h, 0.f);
        ar.H[idx] = h;
    }
}

// ---------------------------------------------------------------------------
// Ent aggregation (CSR, no atomics) + mean + ReLU. 40 thr/node.
// ---------------------------------------------------------------------------
__global__ __launch_bounds__(256) void agg_ent_csr(
    const int* __restrict__ rowptr, const int4* __restrict__ pack,
    const float* __restrict__ arI, const float* __restrict__ arO,
    const float* __restrict__ aeI, const float* __restrict__ aeO,
    const float* __restrict__ atI, const float* __restrict__ atO,
    float* __restrict__ H, int relu)
{
    int tid = blockIdx.x * 256 + threadIdx.x;
    int n = tid / 40;
    if (n >= N_ENT) return;
    int g = tid - n * 40;
    int c = g * 4;
    int b = rowptr[n], e = rowptr[n + 1];
    float ax = 0.f, ay = 0.f, az = 0.f, aw = 0.f;
    for (int j = b; j < e; ++j) {
        int4 p = pack[j];
        const float* t1 = (p.w ? arO : arI) + (size_t)p.x * 160 + c;
        const float* t2 = (p.w ? aeO : aeI) + (size_t)p.y * 160 + c;
        const float* t3 = (p.w ? atO : atI) + (size_t)p.z * 160 + c;
        float4 v1 = *(const float4*)t1;
        float4 v2 = *(const float4*)t2;
        float4 v3 = *(const float4*)t3;
        ax += v1.x + v2.x + v3.x;
        ay += v1.y + v2.y + v3.y;
        az += v1.z + v2.z + v3.z;
        aw += v1.w + v2.w + v3.w;
    }
    size_t idx = (size_t)n * 160 + c;
    float4 h = *(const float4*)(H + idx);
    if (e > b) {
        float s = 1.0f / (float)(e - b);
        h.x = fmaf(ax, s, h.x); h.y = fmaf(ay, s, h.y);
        h.z = fmaf(az, s, h.z); h.w = fmaf(aw, s, h.w);
    }
    if (relu) {
        h.x = fmaxf(h.x, 0.f); h.y = fmaxf(h.y, 0.f);
        h.z = fmaxf(h.z, 0.f); h.w = fmaxf(h.w, 0.f);
    }
    *(float4*)(H + idx) = h;
}

// ---------------------------------------------------------------------------
// Heads P3b (packed): role 0 -> ent logstd-agg + sample; role 1 -> rel.
// ---------------------------------------------------------------------------
__global__ __launch_bounds__(256) void heads_p3b(
    const int* __restrict__ rowptrE, const int4* __restrict__ packE,
    const float* __restrict__ arI, const float* __restrict__ arO,
    const float* __restrict__ aeI, const float* __restrict__ aeO,
    const float* __restrict__ atI, const float* __restrict__ atO,
    const float* __restrict__ HsE, const float* __restrict__ meanE,
    const float* __restrict__ noiseE, float* __restrict__ outE,
    const int* __restrict__ rowptrR, const int4* __restrict__ packR,
    const float* __restrict__ bmI, const float* __restrict__ bmO,
    const float* __restrict__ brI, const float* __restrict__ brO,
    const float* __restrict__ HsR, const float* __restrict__ meanR,
    const float* __restrict__ noiseR, float* __restrict__ outR)
{
    __shared__ float part[6][40][4];
    const int t = threadIdx.x;
    if (blockIdx.y == 0) {
        int tid = blockIdx.x * 256 + t;
        int n = tid / 40;
        if (n >= N_ENT) return;
        int g = tid - n * 40;
        int c = g * 4;
        int b = rowptrE[n], e = rowptrE[n + 1];
        float ax = 0.f, ay = 0.f, az = 0.f, aw = 0.f;
        for (int j = b; j < e; ++j) {
            int4 p = packE[j];
            const float* t1 = (p.w ? arO : arI) + (size_t)p.x * 160 + c;
            const float* t2 = (p.w ? aeO : aeI) + (size_t)p.y * 160 + c;
            const float* t3 = (p.w ? atO : atI) + (size_t)p.z * 160 + c;
            float4 v1 = *(const float4*)t1;
            float4 v2 = *(const float4*)t2;
            float4 v3 = *(const float4*)t3;
            ax += v1.x + v2.x + v3.x;
            ay += v1.y + v2.y + v3.y;
            az += v1.z + v2.z + v3.z;
            aw += v1.w + v2.w + v3.w;
        }
        size_t idx = (size_t)n * 160 + c;
        float4 h = *(const float4*)(HsE + idx);
        if (e > b) {
            float s = 1.0f / (float)(e - b);
            h.x = fmaf(ax, s, h.x); h.y = fmaf(ay, s, h.y);
            h.z = fmaf(az, s, h.z); h.w = fmaf(aw, s, h.w);
        }
        float4 mn = *(const float4*)(meanE + idx);
        float4 nz = *(const float4*)(noiseE + idx);
        float4 zv;
        zv.x = fmaf(nz.x, expf(h.x), mn.x);
        zv.y = fmaf(nz.y, expf(h.y), mn.y);
        zv.z = fmaf(nz.z, expf(h.z), mn.z);
        zv.w = fmaf(nz.w, expf(h.w), mn.w);
        *(float4*)(outE + idx) = zv;
        return;
    }
    // role 1: rel logstd agg + sample
    int n = blockIdx.x;
    if (n >= N_RELN) return;
    int g = t % 40, s = t / 40;
    int b = rowptrR[n], e = rowptrR[n + 1];
    if (s < 6) {
        int c = g * 4;
        float ax = 0.f, ay = 0.f, az = 0.f, aw = 0.f;
        for (int j = b + s; j < e; j += 6) {
            int4 p = packR[j];
            const float* pm = (p.w ? bmO : bmI) + (size_t)p.x * 160 + c;
            const float* pr = (p.w ? brO : brI) + (size_t)p.y * 160 + c;
            float4 vm = *(const float4*)pm;
            float4 vr = *(const float4*)pr;
            ax += vm.x + vr.x; ay += vm.y + vr.y;
            az += vm.z + vr.z; aw += vm.w + vr.w;
        }
        part[s][g][0] = ax; part[s][g][1] = ay;
        part[s][g][2] = az; part[s][g][3] = aw;
    }
    __syncthreads();
    if (t < 160) {
        int gg = t >> 2, q = t & 3;
        float acc = 0.f;
#pragma unroll
        for (int s2 = 0; s2 < 6; ++s2) acc += part[s2][gg][q];
        size_t idx = (size_t)n * 160 + t;
        float h = HsR[idx];
        int d = e - b;
        if (d > 0) h = fmaf(acc, 1.0f / (float)d, h);
        outR[idx] = fmaf(noiseR[idx], expf(h), meanR[idx]);
    }
}

// ---------------------------------------------------------------------------
// CSR build (packed x2): count -> fast hierarchical scan -> scatter(pack)
// ---------------------------------------------------------------------------
__global__ void count2(const int* __restrict__ d1, int E1, int* __restrict__ c1,
                       const int* __restrict__ d2, int E2, int* __restrict__ c2)
{
    int e = blockIdx.x * 256 + threadIdx.x;
    if (blockIdx.y == 0) { if (e < E1) atomicAdd(&c1[d1[e]], 1); }
    else                 { if (e < E2) atomicAdd(&c2[d2[e]], 1); }
}

// 1024 threads: per-thread chunk sum -> wave shfl inclusive scan -> 16-wave
// LDS offset scan -> writeback. Replaces the 48 µs serial single-wave scan.
static __device__ void scan_body(int* __restrict__ cnt, int* __restrict__ rowptr,
                                 int n, int* __restrict__ wsum)
{
    int t = threadIdx.x, lane = t & 63, w = t >> 6;
    int chunk = (n + 1023) >> 10;
    int s0 = t * chunk; if (s0 > n) s0 = n;
    int s1 = s0 + chunk; if (s1 > n) s1 = n;
    int local = 0;
    for (int i = s0; i < s1; ++i) local += cnt[i];
    int incl = local;
#pragma unroll
    for (int d = 1; d < 64; d <<= 1) {
        int v = __shfl_up(incl, d, 64);
        if (lane >= d) incl += v;
    }
    if (lane == 63) wsum[w] = incl;
    __syncthreads();
    if (t == 0) {
        int a = 0;
#pragma unroll
        for (int i = 0; i < 16; ++i) { int v = wsum[i]; wsum[i] = a; a += v; }
    }
    __syncthreads();
    int acc = wsum[w] + incl - local;   // exclusive prefix for this thread
    for (int i = s0; i < s1; ++i) {
        int v = cnt[i];
        rowptr[i] = acc;
        cnt[i] = acc;       // cnt becomes scatter cursor
        acc += v;
    }
    if (t == 1023) rowptr[n] = acc;     // total (thread 1023 covers the tail)
}

__global__ __launch_bounds__(1024) void scan2(int* cntE, int* rowptrE, int* cntR, int* rowptrR)
{
    __shared__ int wsum[16];
    if (blockIdx.x == 0) scan_body(cntE, rowptrE, N_ENT, wsum);
    else                 scan_body(cntR, rowptrR, N_RELN, wsum);
}

__global__ void scatter2(
    const int* __restrict__ d1, const int* __restrict__ a10, const int* __restrict__ a11,
    const int* __restrict__ a12, const int* __restrict__ inv1, int E1,
    int* __restrict__ cur1, int4* __restrict__ pk1,
    const int* __restrict__ d2, const int* __restrict__ a20, const int* __restrict__ a21,
    const int* __restrict__ inv2, int E2,
    int* __restrict__ cur2, int4* __restrict__ pk2)
{
    int e = blockIdx.x * 256 + threadIdx.x;
    if (blockIdx.y == 0) {
        if (e < E1) {
            int p = atomicAdd(&cur1[d1[e]], 1);
            int4 v; v.x = a10[e]; v.y = a11[e]; v.z = a12[e]; v.w = inv1[e];
            pk1[p] = v;
        }
    } else {
        if (e < E2) {
            int p = atomicAdd(&cur2[d2[e]], 1);
            int4 v; v.x = a20[e]; v.y = a21[e]; v.z = 0; v.w = inv2[e];
            pk2[p] = v;
        }
    }
}

// ---------------------------------------------------------------------------
extern "C" void kernel_launch(void* const* d_in, const int* in_sizes, int n_in,
                              void* d_out, int out_size, void* d_ws, size_t ws_size,
                              hipStream_t stream)
{
    const float* ent0   = (const float*)d_in[0];
    const float* rel0   = (const float*)d_in[1];
    const float* tim0   = (const float*)d_in[2];
    const float* meta0  = (const float*)d_in[3];
    const float* noiseE = (const float*)d_in[4];
    const float* noiseR = (const float*)d_in[5];
    const float* entWI  = (const float*)d_in[6];
    const float* entWIb = (const float*)d_in[7];
    const float* entWO  = (const float*)d_in[8];
    const float* entWOb = (const float*)d_in[9];
    const float* entWS  = (const float*)d_in[10];
    const float* entWSb = (const float*)d_in[11];
    const float* entWT  = (const float*)d_in[12];
    const float* entWTb = (const float*)d_in[13];
    const float* relWI  = (const float*)d_in[14];
    const float* relWIb = (const float*)d_in[15];
    const float* relWO  = (const float*)d_in[16];
    const float* relWOb = (const float*)d_in[17];
    const float* relWS  = (const float*)d_in[18];
    const float* relWSb = (const float*)d_in[19];
    const float* relWM  = (const float*)d_in[20];
    const float* relWMb = (const float*)d_in[21];
    const int* src    = (const int*)d_in[22];
    const int* dst    = (const int*)d_in[23];
    const int* e_rel  = (const int*)d_in[24];
    const int* e_time = (const int*)d_in[25];
    const int* e_inv  = (const int*)d_in[26];
    const int* p_src  = (const int*)d_in[27];
    const int* p_dst  = (const int*)d_in[28];
    const int* p_rel  = (const int*)d_in[29];
    const int* p_inv  = (const int*)d_in[30];

    float* out = (float*)d_out;
    float* OUT_ent   = out + 0;
    float* OUT_ento  = out + 3200000;
    float* OUT_rel   = out + 6400000;
    float* OUT_relo  = out + 6464000;
    float* OUT_tim   = out + 6528000;
    float* OUT_timo  = out + 6557280;
    float* OUT_meta  = out + 6586560;
    float* OUT_metao = out + 6714560;

    // ---- workspace carve-out (~76 MB, proven budget) ----
    char* wsp = (char*)d_ws;
    size_t off = 0;
    auto allocF = [&](size_t n) -> float* {
        float* p = (float*)(wsp + off);
        off += ((n * sizeof(float) + 255) & ~(size_t)255);
        return p;
    };
    auto allocU = [&](size_t n) -> ushort* {
        ushort* p = (ushort*)(wsp + off);
        off += ((n * sizeof(ushort) + 255) & ~(size_t)255);
        return p;
    };
    auto allocI = [&](size_t n) -> int* {
        int* p = (int*)(wsp + off);
        off += ((n * sizeof(int) + 255) & ~(size_t)255);
        return p;
    };
    float* AI      = allocF(3200000);
    float* AO      = allocF(3200000);
    float* B1v     = allocF(3200000);   // ent1 / Hs(logstd_e) / ent_o1
    float* B5v     = allocF(3200000);   // mean_e / z_e
    float* tim1    = allocF(29280);
    float* tim_o1  = allocF(29280);
    float* rel1    = allocF(64000);
    float* rel_o1  = allocF(64000);
    float* meta1   = allocF(128000);
    float* meta_o1 = allocF(128000);
    float* arI  = allocF(64000);
    float* arO  = allocF(64000);
    float* atI  = allocF(58560);
    float* atO  = allocF(58560);
    float* bmI  = allocF(128000);
    float* bmO  = allocF(128000);
    float* brI  = allocF(64000);
    float* brO  = allocF(64000);
    float* ar5I = allocF(64000);
    float* ar5O = allocF(64000);
    float* at5I = allocF(58560);
    float* at5O = allocF(58560);
    float* bm5I = allocF(128000);
    float* bm5O = allocF(128000);
    float* br5I = allocF(64000);
    float* br5O = allocF(64000);
    float* hR4  = allocF(64000);        // mean_r
    float* hR5  = allocF(64000);        // Hs for rel logstd
    float* zR   = allocF(64000);
    ushort* Ahg = allocU(3200000);      // activation hi
    ushort* Alg = allocU(3200000);      // activation lo
    ushort* Bhg = allocU(18 * 25600);   // weight hi (transposed)
    ushort* Blg = allocU(18 * 25600);
    int*  cntE    = allocI(N_ENT);
    int*  rowptrE = allocI(N_ENT + 1);
    int4* packE   = (int4*)allocI(NE * 4);
    int*  cntR    = allocI(N_RELN);
    int*  rowptrR = allocI(N_RELN + 1);
    int4* packR   = (int4*)allocI(NPE * 4);
    if (ws_size < off) return;  // loud failure (output stays poisoned)

    // ---- CSR build (packed) ----
    hipMemsetAsync(cntE, 0, N_ENT * sizeof(int), stream);
    hipMemsetAsync(cntR, 0, N_RELN * sizeof(int), stream);
    count2<<<dim3(782, 2), 256, 0, stream>>>(dst, NE, cntE, p_dst, NPE, cntR);
    scan2<<<2, 1024, 0, stream>>>(cntE, rowptrE, cntR, rowptrR);
    scatter2<<<dim3(782, 2), 256, 0, stream>>>(dst, e_rel, src, e_time, e_inv, NE, cntE, packE,
                                               p_dst, p_rel, p_src, p_inv, NPE, cntR, packR);

    // ---- weight prep: slots li*3 + {0:WIent, 1:WOent, 2:WS} ----
    BPrep bp;
    for (int li = 0; li < 6; ++li) {
        bp.W[li * 3 + 0] = entWI + (size_t)li * 64000 + 25600;
        bp.W[li * 3 + 1] = entWO + (size_t)li * 64000 + 25600;
        bp.W[li * 3 + 2] = entWS + (size_t)li * 25600;
    }
    bprep<<<(18 * 160 * 20 + 255) / 256, 256, 0, stream>>>(bp, Bhg, Blg);

    auto bigmf = [&](int li, float* entOut) -> BigMF {
        BigMF bb;
        for (int j = 0; j < 3; ++j) {
            bb.bh[j] = Bhg + (size_t)(li * 3 + j) * 25600;
            bb.bl[j] = Blg + (size_t)(li * 3 + j) * 25600;
        }
        bb.bias[0] = nullptr; bb.bias[1] = nullptr; bb.bias[2] = entWSb + li * 160;
        bb.C[0] = AI; bb.C[1] = AO; bb.C[2] = entOut;
        return bb;
    };

    // ---- normal stage (li in {0,1,2,3}): 3 launches ----
    auto stage = [&](int li, const float* entIn, const float* relIn, const float* timIn,
                     const float* metaIn, float* entOut, float* timOut,
                     float* relOut, float* metaOut, int act) {
        const float* WI  = entWI + (size_t)li * 64000;
        const float* WO  = entWO + (size_t)li * 64000;
        const float* rWI = relWI + (size_t)li * 51200;
        const float* rWO = relWO + (size_t)li * 51200;

        SmallBatch sb{};
        int ns = 0;
        sb.d[ns++] = SmallDesc{relIn,  WI,          entWIb + li * 160, arI,    N_RELN, 160, 160, 160, 0};
        sb.d[ns++] = SmallDesc{relIn,  WO,          entWOb + li * 160, arO,    N_RELN, 160, 160, 160, 0};
        sb.d[ns++] = SmallDesc{timIn,  WI + 51200,  nullptr,           atI,    N_TIME,  80, 160, 160, 0};
        sb.d[ns++] = SmallDesc{timIn,  WO + 51200,  nullptr,           atO,    N_TIME,  80, 160, 160, 0};
        if (timOut)
            sb.d[ns++] = SmallDesc{timIn, entWT + (size_t)li * 6400, entWTb + li * 80,
                                   timOut, N_TIME, 80, 80, 80, act};
        sb.d[ns++] = SmallDesc{metaIn, rWI,         relWIb + li * 160, bmI,    N_META, 160, 160, 160, 0};
        sb.d[ns++] = SmallDesc{metaIn, rWO,         relWOb + li * 160, bmO,    N_META, 160, 160, 160, 0};
        sb.d[ns++] = SmallDesc{relIn,  rWI + 25600, nullptr,           brI,    N_RELN, 160, 160, 160, 0};
        sb.d[ns++] = SmallDesc{relIn,  rWO + 25600, nullptr,           brO,    N_RELN, 160, 160, 160, 0};
        sb.d[ns++] = SmallDesc{relIn,  relWS + (size_t)li * 25600, relWSb + li * 160,
                               relOut, N_RELN, 160, 160, 160, 0};
        if (metaOut)
            sb.d[ns++] = SmallDesc{metaIn, relWM + (size_t)li * 25600, relWMb + li * 160,
                                   metaOut, N_META, 160, 160, 160, act};
        stage_p1<<<dim3(128, ns + 1), 256, 0, stream>>>(sb, ns, entIn, Ahg, Alg, 400000);

        AggRelA ar{rowptrR, packR, bmI, bmO, brI, brO, relOut, act};
        stage_p2<<<dim3(400, 4), 256, 0, stream>>>(Ahg, Alg, N_ENT, bigmf(li, entOut), ar);

        agg_ent_csr<<<3125, 256, 0, stream>>>(
            rowptrE, packE, arI, arO, AI, AO, atI, atO, entOut, act);
    };

    // ---- encoder ----
    stage(0, ent0, rel0, tim0, meta0, B1v, tim1, rel1, meta1, 1);
    stage(1, B1v, rel1, tim1, meta1, OUT_ent, OUT_tim, OUT_rel, OUT_meta, 0);

    // ---- variational heads (li=4 mean, li=5 log_std), fused sampling: 5 launches ----
    {
        const float* WI4  = entWI + (size_t)4 * 64000;
        const float* WO4  = entWO + (size_t)4 * 64000;
        const float* WI5  = entWI + (size_t)5 * 64000;
        const float* WO5  = entWO + (size_t)5 * 64000;
        const float* rWI4 = relWI + (size_t)4 * 51200;
        const float* rWO4 = relWO + (size_t)4 * 51200;
        const float* rWI5 = relWI + (size_t)5 * 51200;
        const float* rWO5 = relWO + (size_t)5 * 51200;

        SmallBatch sb{};
        int ns = 0;
        sb.d[ns++] = SmallDesc{OUT_rel,  WI4,          entWIb + 4 * 160, arI,  N_RELN, 160, 160, 160, 0};
        sb.d[ns++] = SmallDesc{OUT_rel,  WO4,          entWOb + 4 * 160, arO,  N_RELN, 160, 160, 160, 0};
        sb.d[ns++] = SmallDesc{OUT_tim,  WI4 + 51200,  nullptr,          atI,  N_TIME,  80, 160, 160, 0};
        sb.d[ns++] = SmallDesc{OUT_tim,  WO4 + 51200,  nullptr,          atO,  N_TIME,  80, 160, 160, 0};
        sb.d[ns++] = SmallDesc{OUT_meta, rWI4,         relWIb + 4 * 160, bmI,  N_META, 160, 160, 160, 0};
        sb.d[ns++] = SmallDesc{OUT_meta, rWO4,         relWOb + 4 * 160, bmO,  N_META, 160, 160, 160, 0};
        sb.d[ns++] = SmallDesc{OUT_rel,  rWI4 + 25600, nullptr,          brI,  N_RELN, 160, 160, 160, 0};
        sb.d[ns++] = SmallDesc{OUT_rel,  rWO4 + 25600, nullptr,          brO,  N_RELN, 160, 160, 160, 0};
        sb.d[ns++] = SmallDesc{OUT_rel,  relWS + (size_t)4 * 25600, relWSb + 4 * 160,
                               hR4, N_RELN, 160, 160, 160, 0};
        sb.d[ns++] = SmallDesc{OUT_rel,  WI5,          entWIb + 5 * 160, ar5I, N_RELN, 160, 160, 160, 0};
        sb.d[ns++] = SmallDesc{OUT_rel,  WO5,          entWOb + 5 * 160, ar5O, N_RELN, 160, 160, 160, 0};
        sb.d[ns++] = SmallDesc{OUT_tim,  WI5 + 51200,  nullptr,          at5I, N_TIME,  80, 160, 160, 0};
        sb.d[ns++] = SmallDesc{OUT_tim,  WO5 + 51200,  nullptr,          at5O, N_TIME,  80, 160, 160, 0};
        sb.d[ns++] = SmallDesc{OUT_meta, rWI5,         relWIb + 5 * 160, bm5I, N_META, 160, 160, 160, 0};
        sb.d[ns++] = SmallDesc{OUT_meta, rWO5,         relWOb + 5 * 160, bm5O, N_META, 160, 160, 160, 0};
        sb.d[ns++] = SmallDesc{OUT_rel,  rWI5 + 25600, nullptr,          br5I, N_RELN, 160, 160, 160, 0};
        sb.d[ns++] = SmallDesc{OUT_rel,  rWO5 + 25600, nullptr,          br5O, N_RELN, 160, 160, 160, 0};
        sb.d[ns++] = SmallDesc{OUT_rel,  relWS + (size_t)5 * 25600, relWSb + 5 * 160,
                               hR5, N_RELN, 160, 160, 160, 0};
        stage_p1<<<dim3(128, ns + 1), 256, 0, stream>>>(sb, ns, OUT_ent, Ahg, Alg, 400000);

        // P2a: mean-head big GEMMs + rel mean agg -> hR4
        AggRelA ar4{rowptrR, packR, bmI, bmO, brI, brO, hR4, 0};
        stage_p2<<<dim3(400, 4), 256, 0, stream>>>(Ahg, Alg, N_ENT, bigmf(4, B5v), ar4);
        // P3a: ent mean agg -> B5v
        agg_ent_csr<<<3125, 256, 0, stream>>>(
            rowptrE, packE, arI, arO, AI, AO, atI, atO, B5v, 0);
        // P2b: logstd-head big GEMMs (no rel role)
        AggRelA arNull{};
        stage_p2<<<dim3(313, 3), 256, 0, stream>>>(Ahg, Alg, N_ENT, bigmf(5, B1v), arNull);
        // P3b: ent logstd agg + sample -> B5v ; rel logstd agg + sample -> zR
        heads_p3b<<<dim3(3125, 2), 256, 0, stream>>>(
            rowptrE, packE, ar5I, ar5O, AI, AO, at5I, at5O, B1v, B5v, noiseE, B5v,
            rowptrR, packR, bm5I, bm5O, br5I, br5O, hR5, hR4, noiseR, zR);
    }

    // ---- decoder (layers 2,3) ----
    stage(2, B5v, zR, OUT_tim, OUT_meta, B1v, tim_o1, rel_o1, meta_o1, 1);
    stage(3, B1v, rel_o1, tim_o1, meta_o1, OUT_ento, OUT_timo, OUT_relo, OUT_metao, 0);
}

// Round 8
// 851.194 us; speedup vs baseline: 1.1007x; 1.1007x over previous
//
#include <hip/hip_runtime.h>
#include <math.h>

#define N_ENT     20000
#define N_RELN    400
#define N_TIME    366
#define N_META    800
#define NE        200000
#define NPE       80000
// dims: ENT=160, REL=160, TIME=80; DIN_E=400, DIN_R=320; NL=6

typedef __attribute__((ext_vector_type(8))) short short8;
typedef __attribute__((ext_vector_type(4))) float f32x4;

static __device__ __forceinline__ ushort f2bf(float x) {
    unsigned u = __float_as_uint(x);
    unsigned r = (u + 0x7FFF + ((u >> 16) & 1)) >> 16;   // RN-to-even
    return (ushort)r;
}
static __device__ __forceinline__ float bf2f(ushort b) {
    return __uint_as_float(((unsigned)b) << 16);
}

// ---------------------------------------------------------------------------
// Weight prep: 18 big 160x160 matrices -> transposed [col][k] bf16 hi/lo.
// ---------------------------------------------------------------------------
struct BPrep { const float* W[18]; };

__global__ __launch_bounds__(256) void bprep(BPrep bp, ushort* __restrict__ hi, ushort* __restrict__ lo)
{
    int idx = blockIdx.x * 256 + threadIdx.x;       // (s, n, kc): 18*160*20
    if (idx >= 18 * 160 * 20) return;
    int s = idx / 3200, rem = idx - s * 3200;
    int n = rem / 20, kc = rem - n * 20;
    const float* __restrict__ W = bp.W[s];
    ushort h[8], l[8];
#pragma unroll
    for (int j = 0; j < 8; ++j) {
        float x = W[(kc * 8 + j) * 160 + n];
        h[j] = f2bf(x);
        l[j] = f2bf(x - bf2f(h[j]));
    }
    size_t o = (size_t)s * 25600 + n * 160 + kc * 8;
    *(short8*)(hi + o) = *(short8*)h;
    *(short8*)(lo + o) = *(short8*)l;
}

// ---------------------------------------------------------------------------
// Stage P1 (packed): role < ns -> register-tiled small GEMM (PROVEN round 6);
// role == ns -> aprep grid-stride over nitems=400000.
// grid.x = 800 (round-7 regression: 128 starved the aprep role to 2 waves/CU,
// 66 us; GEMM roles' surplus blocks early-exit on mb>=nmb).
// ---------------------------------------------------------------------------
struct SmallDesc {
    const float* A;
    const float* B;
    const float* bias;
    float*       C;
    int M, K, N, ldb, relu;
};
struct SmallBatch { SmallDesc d[18]; };

#define FMA4(acc, a, b) { acc.x = fmaf(a, b.x, acc.x); acc.y = fmaf(a, b.y, acc.y); \
                          acc.z = fmaf(a, b.z, acc.z); acc.w = fmaf(a, b.w, acc.w); }

__global__ __launch_bounds__(256) void stage_p1(SmallBatch sb, int ns,
    const float* __restrict__ ain, ushort* __restrict__ ah, ushort* __restrict__ al, int nitems)
{
    int role = blockIdx.y;
    int tid = blockIdx.x * 256 + threadIdx.x;
    if (role == ns) {
        int stride = gridDim.x * 256;
        for (int i = tid; i < nitems; i += stride) {
            const float* p = ain + (size_t)i * 8;
            ushort h[8], l[8];
#pragma unroll
            for (int j = 0; j < 8; ++j) {
                float x = p[j];
                h[j] = f2bf(x);
                l[j] = f2bf(x - bf2f(h[j]));
            }
            *(short8*)(ah + (size_t)i * 8) = *(short8*)h;
            *(short8*)(al + (size_t)i * 8) = *(short8*)l;
        }
        return;
    }
    SmallDesc dd = sb.d[role];
    int ng = dd.N >> 2;
    int mb = tid / ng;
    int nmb = (dd.M + 3) >> 2;
    if (mb >= nmb) return;
    int g = tid - mb * ng;
    int r0 = mb * 4;
    int mlast = dd.M - 1;
    const float* A0 = dd.A + (size_t)min(r0 + 0, mlast) * dd.K;
    const float* A1 = dd.A + (size_t)min(r0 + 1, mlast) * dd.K;
    const float* A2 = dd.A + (size_t)min(r0 + 2, mlast) * dd.K;
    const float* A3 = dd.A + (size_t)min(r0 + 3, mlast) * dd.K;
    const float* Bp = dd.B + g * 4;
    float4 c0 = {0,0,0,0}, c1 = {0,0,0,0}, c2 = {0,0,0,0}, c3 = {0,0,0,0};
    for (int k = 0; k < dd.K; k += 4) {
        float4 b0 = *(const float4*)(Bp + (size_t)(k + 0) * dd.ldb);
        float4 b1 = *(const float4*)(Bp + (size_t)(k + 1) * dd.ldb);
        float4 b2 = *(const float4*)(Bp + (size_t)(k + 2) * dd.ldb);
        float4 b3 = *(const float4*)(Bp + (size_t)(k + 3) * dd.ldb);
        float4 a0 = *(const float4*)(A0 + k);
        float4 a1 = *(const float4*)(A1 + k);
        float4 a2 = *(const float4*)(A2 + k);
        float4 a3 = *(const float4*)(A3 + k);
        FMA4(c0, a0.x, b0) FMA4(c0, a0.y, b1) FMA4(c0, a0.z, b2) FMA4(c0, a0.w, b3)
        FMA4(c1, a1.x, b0) FMA4(c1, a1.y, b1) FMA4(c1, a1.z, b2) FMA4(c1, a1.w, b3)
        FMA4(c2, a2.x, b0) FMA4(c2, a2.y, b1) FMA4(c2, a2.z, b2) FMA4(c2, a2.w, b3)
        FMA4(c3, a3.x, b0) FMA4(c3, a3.y, b1) FMA4(c3, a3.z, b2) FMA4(c3, a3.w, b3)
    }
    float4 bv = {0,0,0,0};
    if (dd.bias) bv = *(const float4*)(dd.bias + g * 4);
    c0.x += bv.x; c0.y += bv.y; c0.z += bv.z; c0.w += bv.w;
    c1.x += bv.x; c1.y += bv.y; c1.z += bv.z; c1.w += bv.w;
    c2.x += bv.x; c2.y += bv.y; c2.z += bv.z; c2.w += bv.w;
    c3.x += bv.x; c3.y += bv.y; c3.z += bv.z; c3.w += bv.w;
    if (dd.relu) {
        c0.x = fmaxf(c0.x, 0.f); c0.y = fmaxf(c0.y, 0.f); c0.z = fmaxf(c0.z, 0.f); c0.w = fmaxf(c0.w, 0.f);
        c1.x = fmaxf(c1.x, 0.f); c1.y = fmaxf(c1.y, 0.f); c1.z = fmaxf(c1.z, 0.f); c1.w = fmaxf(c1.w, 0.f);
        c2.x = fmaxf(c2.x, 0.f); c2.y = fmaxf(c2.y, 0.f); c2.z = fmaxf(c2.z, 0.f); c2.w = fmaxf(c2.w, 0.f);
        c3.x = fmaxf(c3.x, 0.f); c3.y = fmaxf(c3.y, 0.f); c3.z = fmaxf(c3.z, 0.f); c3.w = fmaxf(c3.w, 0.f);
    }
    float* C = dd.C + (size_t)r0 * dd.N + g * 4;
    if (r0 + 0 < dd.M) *(float4*)(C + 0 * (size_t)dd.N) = c0;
    if (r0 + 1 < dd.M) *(float4*)(C + 1 * (size_t)dd.N) = c1;
    if (r0 + 2 < dd.M) *(float4*)(C + 2 * (size_t)dd.N) = c2;
    if (r0 + 3 < dd.M) *(float4*)(C + 3 * (size_t)dd.N) = c3;
}

// ---------------------------------------------------------------------------
// Stage P2 (packed): roles 0..2 -> MFMA split-bf16 big GEMM (round-3 proven
// body); role 3 -> rel aggregation (6 segments x 40 col-groups, 256 thr).
// ---------------------------------------------------------------------------
struct BigMF {
    const ushort* bh[3];
    const ushort* bl[3];
    const float*  bias[3];
    float*        C[3];
};
struct AggRelA {
    const int* rowptr;
    const int4* pack;
    const float *bmI, *bmO, *brI, *brO;
    float* H;
    int relu;
};

__global__ __launch_bounds__(256, 4) void stage_p2(
    const ushort* __restrict__ Ah, const ushort* __restrict__ Al, int M,
    BigMF bb, AggRelA ar)
{
    __shared__ ushort Ahi[64][40], Alo[64][40];
    __shared__ ushort Bhi[160][40], Blo[160][40];
    __shared__ float part[6][40][4];
    const int role = blockIdx.y;
    const int t = threadIdx.x;

    if (role < 3) {
        const int m0 = blockIdx.x * 64;
        if (m0 >= M) return;
        const ushort* __restrict__ Bh = bb.bh[role];
        const ushort* __restrict__ Bl = bb.bl[role];
        const float*  __restrict__ bias = bb.bias[role];
        float* __restrict__ C = bb.C[role];
        const int lane = t & 63, w = t >> 6;
        const int fr = lane & 15, fq = lane >> 4;

        f32x4 acc[10];
#pragma unroll
        for (int i = 0; i < 10; ++i) acc[i] = (f32x4){0.f, 0.f, 0.f, 0.f};

        for (int k0 = 0; k0 < 160; k0 += 32) {
            {
                int r = t >> 2, kc = t & 3;
                int row = m0 + r;
                short8 vh = {0,0,0,0,0,0,0,0}, vl = {0,0,0,0,0,0,0,0};
                if (row < M) {
                    size_t o = (size_t)row * 160 + k0 + kc * 8;
                    vh = *(const short8*)(Ah + o);
                    vl = *(const short8*)(Al + o);
                }
                *(short8*)&Ahi[r][kc * 8] = vh;
                *(short8*)&Alo[r][kc * 8] = vl;
            }
#pragma unroll
            for (int i = 0; i < 3; ++i) {
                int idx = t + i * 256;
                if (idx < 640) {
                    int col = idx >> 2, kc = idx & 3;
                    size_t o = (size_t)col * 160 + k0 + kc * 8;
                    *(short8*)&Bhi[col][kc * 8] = *(const short8*)(Bh + o);
                    *(short8*)&Blo[col][kc * 8] = *(const short8*)(Bl + o);
                }
            }
            __syncthreads();
            short8 ahv = *(const short8*)&Ahi[w * 16 + fr][fq * 8];
            short8 alv = *(const short8*)&Alo[w * 16 + fr][fq * 8];
#pragma unroll
            for (int tt = 0; tt < 10; ++tt) {
                short8 bh = *(const short8*)&Bhi[tt * 16 + fr][fq * 8];
                short8 bl = *(const short8*)&Blo[tt * 16 + fr][fq * 8];
                acc[tt] = __builtin_amdgcn_mfma_f32_16x16x32_bf16(ahv, bh, acc[tt], 0, 0, 0);
                acc[tt] = __builtin_amdgcn_mfma_f32_16x16x32_bf16(alv, bh, acc[tt], 0, 0, 0);
                acc[tt] = __builtin_amdgcn_mfma_f32_16x16x32_bf16(ahv, bl, acc[tt], 0, 0, 0);
            }
            __syncthreads();
        }
#pragma unroll
        for (int tt = 0; tt < 10; ++tt) {
            int col = tt * 16 + fr;
            float bv = bias ? bias[col] : 0.f;
#pragma unroll
            for (int q = 0; q < 4; ++q) {
                int row = m0 + w * 16 + fq * 4 + q;
                if (row < M) C[(size_t)row * 160 + col] = acc[tt][q] + bv;
            }
        }
        return;
    }

    // role 3: rel aggregation
    int n = blockIdx.x;
    if (n >= N_RELN) return;
    int g = t % 40, s = t / 40;
    int b = ar.rowptr[n], e = ar.rowptr[n + 1];
    if (s < 6) {
        int c = g * 4;
        float ax = 0.f, ay = 0.f, az = 0.f, aw = 0.f;
        for (int j = b + s; j < e; j += 6) {
            int4 p = ar.pack[j];
            const float* pm = (p.w ? ar.bmO : ar.bmI) + (size_t)p.x * 160 + c;
            const float* pr = (p.w ? ar.brO : ar.brI) + (size_t)p.y * 160 + c;
            float4 vm = *(const float4*)pm;
            float4 vr = *(const float4*)pr;
            ax += vm.x + vr.x; ay += vm.y + vr.y;
            az += vm.z + vr.z; aw += vm.w + vr.w;
        }
        part[s][g][0] = ax; part[s][g][1] = ay;
        part[s][g][2] = az; part[s][g][3] = aw;
    }
    __syncthreads();
    if (t < 160) {
        int gg = t >> 2, q = t & 3;
        float acc = 0.f;
#pragma unroll
        for (int s2 = 0; s2 < 6; ++s2) acc += part[s2][gg][q];
        size_t idx = (size_t)n * 160 + t;
        float h = ar.H[idx];
        int d = e - b;
        if (d > 0) h = fmaf(acc, 1.0f / (float)d, h);
        if (ar.relu) h = fmaxf(h, 0.f);
        ar.H[idx] = h;
    }
}

// ---------------------------------------------------------------------------
// Ent aggregation (CSR, no atomics) + mean + ReLU. 40 thr/node.
// ---------------------------------------------------------------------------
__global__ __launch_bounds__(256) void agg_ent_csr(
    const int* __restrict__ rowptr, const int4* __restrict__ pack,
    const float* __restrict__ arI, const float* __restrict__ arO,
    const float* __restrict__ aeI, const float* __restrict__ aeO,
    const float* __restrict__ atI, const float* __restrict__ atO,
    float* __restrict__ H, int relu)
{
    int tid = blockIdx.x * 256 + threadIdx.x;
    int n = tid / 40;
    if (n >= N_ENT) return;
    int g = tid - n * 40;
    int c = g * 4;
    int b = rowptr[n], e = rowptr[n + 1];
    float ax = 0.f, ay = 0.f, az = 0.f, aw = 0.f;
    for (int j = b; j < e; ++j) {
        int4 p = pack[j];
        const float* t1 = (p.w ? arO : arI) + (size_t)p.x * 160 + c;
        const float* t2 = (p.w ? aeO : aeI) + (size_t)p.y * 160 + c;
        const float* t3 = (p.w ? atO : atI) + (size_t)p.z * 160 + c;
        float4 v1 = *(const float4*)t1;
        float4 v2 = *(const float4*)t2;
        float4 v3 = *(const float4*)t3;
        ax += v1.x + v2.x + v3.x;
        ay += v1.y + v2.y + v3.y;
        az += v1.z + v2.z + v3.z;
        aw += v1.w + v2.w + v3.w;
    }
    size_t idx = (size_t)n * 160 + c;
    float4 h = *(const float4*)(H + idx);
    if (e > b) {
        float s = 1.0f / (float)(e - b);
        h.x = fmaf(ax, s, h.x); h.y = fmaf(ay, s, h.y);
        h.z = fmaf(az, s, h.z); h.w = fmaf(aw, s, h.w);
    }
    if (relu) {
        h.x = fmaxf(h.x, 0.f); h.y = fmaxf(h.y, 0.f);
        h.z = fmaxf(h.z, 0.f); h.w = fmaxf(h.w, 0.f);
    }
    *(float4*)(H + idx) = h;
}

// ---------------------------------------------------------------------------
// Heads P3b (packed): role 0 -> ent logstd-agg + sample; role 1 -> rel.
// ---------------------------------------------------------------------------
__global__ __launch_bounds__(256) void heads_p3b(
    const int* __restrict__ rowptrE, const int4* __restrict__ packE,
    const float* __restrict__ arI, const float* __restrict__ arO,
    const float* __restrict__ aeI, const float* __restrict__ aeO,
    const float* __restrict__ atI, const float* __restrict__ atO,
    const float* __restrict__ HsE, const float* __restrict__ meanE,
    const float* __restrict__ noiseE, float* __restrict__ outE,
    const int* __restrict__ rowptrR, const int4* __restrict__ packR,
    const float* __restrict__ bmI, const float* __restrict__ bmO,
    const float* __restrict__ brI, const float* __restrict__ brO,
    const float* __restrict__ HsR, const float* __restrict__ meanR,
    const float* __restrict__ noiseR, float* __restrict__ outR)
{
    __shared__ float part[6][40][4];
    const int t = threadIdx.x;
    if (blockIdx.y == 0) {
        int tid = blockIdx.x * 256 + t;
        int n = tid / 40;
        if (n >= N_ENT) return;
        int g = tid - n * 40;
        int c = g * 4;
        int b = rowptrE[n], e = rowptrE[n + 1];
        float ax = 0.f, ay = 0.f, az = 0.f, aw = 0.f;
        for (int j = b; j < e; ++j) {
            int4 p = packE[j];
            const float* t1 = (p.w ? arO : arI) + (size_t)p.x * 160 + c;
            const float* t2 = (p.w ? aeO : aeI) + (size_t)p.y * 160 + c;
            const float* t3 = (p.w ? atO : atI) + (size_t)p.z * 160 + c;
            float4 v1 = *(const float4*)t1;
            float4 v2 = *(const float4*)t2;
            float4 v3 = *(const float4*)t3;
            ax += v1.x + v2.x + v3.x;
            ay += v1.y + v2.y + v3.y;
            az += v1.z + v2.z + v3.z;
            aw += v1.w + v2.w + v3.w;
        }
        size_t idx = (size_t)n * 160 + c;
        float4 h = *(const float4*)(HsE + idx);
        if (e > b) {
            float s = 1.0f / (float)(e - b);
            h.x = fmaf(ax, s, h.x); h.y = fmaf(ay, s, h.y);
            h.z = fmaf(az, s, h.z); h.w = fmaf(aw, s, h.w);
        }
        float4 mn = *(const float4*)(meanE + idx);
        float4 nz = *(const float4*)(noiseE + idx);
        float4 zv;
        zv.x = fmaf(nz.x, expf(h.x), mn.x);
        zv.y = fmaf(nz.y, expf(h.y), mn.y);
        zv.z = fmaf(nz.z, expf(h.z), mn.z);
        zv.w = fmaf(nz.w, expf(h.w), mn.w);
        *(float4*)(outE + idx) = zv;
        return;
    }
    // role 1: rel logstd agg + sample
    int n = blockIdx.x;
    if (n >= N_RELN) return;
    int g = t % 40, s = t / 40;
    int b = rowptrR[n], e = rowptrR[n + 1];
    if (s < 6) {
        int c = g * 4;
        float ax = 0.f, ay = 0.f, az = 0.f, aw = 0.f;
        for (int j = b + s; j < e; j += 6) {
            int4 p = packR[j];
            const float* pm = (p.w ? bmO : bmI) + (size_t)p.x * 160 + c;
            const float* pr = (p.w ? brO : brI) + (size_t)p.y * 160 + c;
            float4 vm = *(const float4*)pm;
            float4 vr = *(const float4*)pr;
            ax += vm.x + vr.x; ay += vm.y + vr.y;
            az += vm.z + vr.z; aw += vm.w + vr.w;
        }
        part[s][g][0] = ax; part[s][g][1] = ay;
        part[s][g][2] = az; part[s][g][3] = aw;
    }
    __syncthreads();
    if (t < 160) {
        int gg = t >> 2, q = t & 3;
        float acc = 0.f;
#pragma unroll
        for (int s2 = 0; s2 < 6; ++s2) acc += part[s2][gg][q];
        size_t idx = (size_t)n * 160 + t;
        float h = HsR[idx];
        int d = e - b;
        if (d > 0) h = fmaf(acc, 1.0f / (float)d, h);
        outR[idx] = fmaf(noiseR[idx], expf(h), meanR[idx]);
    }
}

// ---------------------------------------------------------------------------
// CSR build (packed x2): count -> fast hierarchical scan -> scatter(pack)
// ---------------------------------------------------------------------------
__global__ void count2(const int* __restrict__ d1, int E1, int* __restrict__ c1,
                       const int* __restrict__ d2, int E2, int* __restrict__ c2)
{
    int e = blockIdx.x * 256 + threadIdx.x;
    if (blockIdx.y == 0) { if (e < E1) atomicAdd(&c1[d1[e]], 1); }
    else                 { if (e < E2) atomicAdd(&c2[d2[e]], 1); }
}

// 1024 threads: per-thread chunk sum -> wave shfl inclusive scan -> 16-wave
// LDS offset scan -> writeback.
static __device__ void scan_body(int* __restrict__ cnt, int* __restrict__ rowptr,
                                 int n, int* __restrict__ wsum)
{
    int t = threadIdx.x, lane = t & 63, w = t >> 6;
    int chunk = (n + 1023) >> 10;
    int s0 = t * chunk; if (s0 > n) s0 = n;
    int s1 = s0 + chunk; if (s1 > n) s1 = n;
    int local = 0;
    for (int i = s0; i < s1; ++i) local += cnt[i];
    int incl = local;
#pragma unroll
    for (int d = 1; d < 64; d <<= 1) {
        int v = __shfl_up(incl, d, 64);
        if (lane >= d) incl += v;
    }
    if (lane == 63) wsum[w] = incl;
    __syncthreads();
    if (t == 0) {
        int a = 0;
#pragma unroll
        for (int i = 0; i < 16; ++i) { int v = wsum[i]; wsum[i] = a; a += v; }
    }
    __syncthreads();
    int acc = wsum[w] + incl - local;   // exclusive prefix for this thread
    for (int i = s0; i < s1; ++i) {
        int v = cnt[i];
        rowptr[i] = acc;
        cnt[i] = acc;       // cnt becomes scatter cursor
        acc += v;
    }
    if (t == 1023) rowptr[n] = acc;     // total (thread 1023 covers the tail)
}

__global__ __launch_bounds__(1024) void scan2(int* cntE, int* rowptrE, int* cntR, int* rowptrR)
{
    __shared__ int wsum[16];
    if (blockIdx.x == 0) scan_body(cntE, rowptrE, N_ENT, wsum);
    else                 scan_body(cntR, rowptrR, N_RELN, wsum);
}

__global__ void scatter2(
    const int* __restrict__ d1, const int* __restrict__ a10, const int* __restrict__ a11,
    const int* __restrict__ a12, const int* __restrict__ inv1, int E1,
    int* __restrict__ cur1, int4* __restrict__ pk1,
    const int* __restrict__ d2, const int* __restrict__ a20, const int* __restrict__ a21,
    const int* __restrict__ inv2, int E2,
    int* __restrict__ cur2, int4* __restrict__ pk2)
{
    int e = blockIdx.x * 256 + threadIdx.x;
    if (blockIdx.y == 0) {
        if (e < E1) {
            int p = atomicAdd(&cur1[d1[e]], 1);
            int4 v; v.x = a10[e]; v.y = a11[e]; v.z = a12[e]; v.w = inv1[e];
            pk1[p] = v;
        }
    } else {
        if (e < E2) {
            int p = atomicAdd(&cur2[d2[e]], 1);
            int4 v; v.x = a20[e]; v.y = a21[e]; v.z = 0; v.w = inv2[e];
            pk2[p] = v;
        }
    }
}

// ---------------------------------------------------------------------------
extern "C" void kernel_launch(void* const* d_in, const int* in_sizes, int n_in,
                              void* d_out, int out_size, void* d_ws, size_t ws_size,
                              hipStream_t stream)
{
    const float* ent0   = (const float*)d_in[0];
    const float* rel0   = (const float*)d_in[1];
    const float* tim0   = (const float*)d_in[2];
    const float* meta0  = (const float*)d_in[3];
    const float* noiseE = (const float*)d_in[4];
    const float* noiseR = (const float*)d_in[5];
    const float* entWI  = (const float*)d_in[6];
    const float* entWIb = (const float*)d_in[7];
    const float* entWO  = (const float*)d_in[8];
    const float* entWOb = (const float*)d_in[9];
    const float* entWS  = (const float*)d_in[10];
    const float* entWSb = (const float*)d_in[11];
    const float* entWT  = (const float*)d_in[12];
    const float* entWTb = (const float*)d_in[13];
    const float* relWI  = (const float*)d_in[14];
    const float* relWIb = (const float*)d_in[15];
    const float* relWO  = (const float*)d_in[16];
    const float* relWOb = (const float*)d_in[17];
    const float* relWS  = (const float*)d_in[18];
    const float* relWSb = (const float*)d_in[19];
    const float* relWM  = (const float*)d_in[20];
    const float* relWMb = (const float*)d_in[21];
    const int* src    = (const int*)d_in[22];
    const int* dst    = (const int*)d_in[23];
    const int* e_rel  = (const int*)d_in[24];
    const int* e_time = (const int*)d_in[25];
    const int* e_inv  = (const int*)d_in[26];
    const int* p_src  = (const int*)d_in[27];
    const int* p_dst  = (const int*)d_in[28];
    const int* p_rel  = (const int*)d_in[29];
    const int* p_inv  = (const int*)d_in[30];

    float* out = (float*)d_out;
    float* OUT_ent   = out + 0;
    float* OUT_ento  = out + 3200000;
    float* OUT_rel   = out + 6400000;
    float* OUT_relo  = out + 6464000;
    float* OUT_tim   = out + 6528000;
    float* OUT_timo  = out + 6557280;
    float* OUT_meta  = out + 6586560;
    float* OUT_metao = out + 6714560;

    // ---- workspace carve-out (~76 MB, proven budget) ----
    char* wsp = (char*)d_ws;
    size_t off = 0;
    auto allocF = [&](size_t n) -> float* {
        float* p = (float*)(wsp + off);
        off += ((n * sizeof(float) + 255) & ~(size_t)255);
        return p;
    };
    auto allocU = [&](size_t n) -> ushort* {
        ushort* p = (ushort*)(wsp + off);
        off += ((n * sizeof(ushort) + 255) & ~(size_t)255);
        return p;
    };
    auto allocI = [&](size_t n) -> int* {
        int* p = (int*)(wsp + off);
        off += ((n * sizeof(int) + 255) & ~(size_t)255);
        return p;
    };
    float* AI      = allocF(3200000);
    float* AO      = allocF(3200000);
    float* B1v     = allocF(3200000);   // ent1 / Hs(logstd_e) / ent_o1
    float* B5v     = allocF(3200000);   // mean_e / z_e
    float* tim1    = allocF(29280);
    float* tim_o1  = allocF(29280);
    float* rel1    = allocF(64000);
    float* rel_o1  = allocF(64000);
    float* meta1   = allocF(128000);
    float* meta_o1 = allocF(128000);
    float* arI  = allocF(64000);
    float* arO  = allocF(64000);
    float* atI  = allocF(58560);
    float* atO  = allocF(58560);
    float* bmI  = allocF(128000);
    float* bmO  = allocF(128000);
    float* brI  = allocF(64000);
    float* brO  = allocF(64000);
    float* ar5I = allocF(64000);
    float* ar5O = allocF(64000);
    float* at5I = allocF(58560);
    float* at5O = allocF(58560);
    float* bm5I = allocF(128000);
    float* bm5O = allocF(128000);
    float* br5I = allocF(64000);
    float* br5O = allocF(64000);
    float* hR4  = allocF(64000);        // mean_r
    float* hR5  = allocF(64000);        // Hs for rel logstd
    float* zR   = allocF(64000);
    ushort* Ahg = allocU(3200000);      // activation hi
    ushort* Alg = allocU(3200000);      // activation lo
    ushort* Bhg = allocU(18 * 25600);   // weight hi (transposed)
    ushort* Blg = allocU(18 * 25600);
    int*  cntE    = allocI(N_ENT);
    int*  rowptrE = allocI(N_ENT + 1);
    int4* packE   = (int4*)allocI(NE * 4);
    int*  cntR    = allocI(N_RELN);
    int*  rowptrR = allocI(N_RELN + 1);
    int4* packR   = (int4*)allocI(NPE * 4);
    if (ws_size < off) return;  // loud failure (output stays poisoned)

    // ---- CSR build (packed) ----
    hipMemsetAsync(cntE, 0, N_ENT * sizeof(int), stream);
    hipMemsetAsync(cntR, 0, N_RELN * sizeof(int), stream);
    count2<<<dim3(782, 2), 256, 0, stream>>>(dst, NE, cntE, p_dst, NPE, cntR);
    scan2<<<2, 1024, 0, stream>>>(cntE, rowptrE, cntR, rowptrR);
    scatter2<<<dim3(782, 2), 256, 0, stream>>>(dst, e_rel, src, e_time, e_inv, NE, cntE, packE,
                                               p_dst, p_rel, p_src, p_inv, NPE, cntR, packR);

    // ---- weight prep: slots li*3 + {0:WIent, 1:WOent, 2:WS} ----
    BPrep bp;
    for (int li = 0; li < 6; ++li) {
        bp.W[li * 3 + 0] = entWI + (size_t)li * 64000 + 25600;
        bp.W[li * 3 + 1] = entWO + (size_t)li * 64000 + 25600;
        bp.W[li * 3 + 2] = entWS + (size_t)li * 25600;
    }
    bprep<<<(18 * 160 * 20 + 255) / 256, 256, 0, stream>>>(bp, Bhg, Blg);

    auto bigmf = [&](int li, float* entOut) -> BigMF {
        BigMF bb;
        for (int j = 0; j < 3; ++j) {
            bb.bh[j] = Bhg + (size_t)(li * 3 + j) * 25600;
            bb.bl[j] = Blg + (size_t)(li * 3 + j) * 25600;
        }
        bb.bias[0] = nullptr; bb.bias[1] = nullptr; bb.bias[2] = entWSb + li * 160;
        bb.C[0] = AI; bb.C[1] = AO; bb.C[2] = entOut;
        return bb;
    };

    // ---- normal stage (li in {0,1,2,3}): 3 launches ----
    auto stage = [&](int li, const float* entIn, const float* relIn, const float* timIn,
                     const float* metaIn, float* entOut, float* timOut,
                     float* relOut, float* metaOut, int act) {
        const float* WI  = entWI + (size_t)li * 64000;
        const float* WO  = entWO + (size_t)li * 64000;
        const float* rWI = relWI + (size_t)li * 51200;
        const float* rWO = relWO + (size_t)li * 51200;

        SmallBatch sb{};
        int ns = 0;
        sb.d[ns++] = SmallDesc{relIn,  WI,          entWIb + li * 160, arI,    N_RELN, 160, 160, 160, 0};
        sb.d[ns++] = SmallDesc{relIn,  WO,          entWOb + li * 160, arO,    N_RELN, 160, 160, 160, 0};
        sb.d[ns++] = SmallDesc{timIn,  WI + 51200,  nullptr,           atI,    N_TIME,  80, 160, 160, 0};
        sb.d[ns++] = SmallDesc{timIn,  WO + 51200,  nullptr,           atO,    N_TIME,  80, 160, 160, 0};
        if (timOut)
            sb.d[ns++] = SmallDesc{timIn, entWT + (size_t)li * 6400, entWTb + li * 80,
                                   timOut, N_TIME, 80, 80, 80, act};
        sb.d[ns++] = SmallDesc{metaIn, rWI,         relWIb + li * 160, bmI,    N_META, 160, 160, 160, 0};
        sb.d[ns++] = SmallDesc{metaIn, rWO,         relWOb + li * 160, bmO,    N_META, 160, 160, 160, 0};
        sb.d[ns++] = SmallDesc{relIn,  rWI + 25600, nullptr,           brI,    N_RELN, 160, 160, 160, 0};
        sb.d[ns++] = SmallDesc{relIn,  rWO + 25600, nullptr,           brO,    N_RELN, 160, 160, 160, 0};
        sb.d[ns++] = SmallDesc{relIn,  relWS + (size_t)li * 25600, relWSb + li * 160,
                               relOut, N_RELN, 160, 160, 160, 0};
        if (metaOut)
            sb.d[ns++] = SmallDesc{metaIn, relWM + (size_t)li * 25600, relWMb + li * 160,
                                   metaOut, N_META, 160, 160, 160, act};
        stage_p1<<<dim3(800, ns + 1), 256, 0, stream>>>(sb, ns, entIn, Ahg, Alg, 400000);

        AggRelA ar{rowptrR, packR, bmI, bmO, brI, brO, relOut, act};
        stage_p2<<<dim3(400, 4), 256, 0, stream>>>(Ahg, Alg, N_ENT, bigmf(li, entOut), ar);

        agg_ent_csr<<<3125, 256, 0, stream>>>(
            rowptrE, packE, arI, arO, AI, AO, atI, atO, entOut, act);
    };

    // ---- encoder ----
    stage(0, ent0, rel0, tim0, meta0, B1v, tim1, rel1, meta1, 1);
    stage(1, B1v, rel1, tim1, meta1, OUT_ent, OUT_tim, OUT_rel, OUT_meta, 0);

    // ---- variational heads (li=4 mean, li=5 log_std), fused sampling: 5 launches ----
    {
        const float* WI4  = entWI + (size_t)4 * 64000;
        const float* WO4  = entWO + (size_t)4 * 64000;
        const float* WI5  = entWI + (size_t)5 * 64000;
        const float* WO5  = entWO + (size_t)5 * 64000;
        const float* rWI4 = relWI + (size_t)4 * 51200;
        const float* rWO4 = relWO + (size_t)4 * 51200;
        const float* rWI5 = relWI + (size_t)5 * 51200;
        const float* rWO5 = relWO + (size_t)5 * 51200;

        SmallBatch sb{};
        int ns = 0;
        sb.d[ns++] = SmallDesc{OUT_rel,  WI4,          entWIb + 4 * 160, arI,  N_RELN, 160, 160, 160, 0};
        sb.d[ns++] = SmallDesc{OUT_rel,  WO4,          entWOb + 4 * 160, arO,  N_RELN, 160, 160, 160, 0};
        sb.d[ns++] = SmallDesc{OUT_tim,  WI4 + 51200,  nullptr,          atI,  N_TIME,  80, 160, 160, 0};
        sb.d[ns++] = SmallDesc{OUT_tim,  WO4 + 51200,  nullptr,          atO,  N_TIME,  80, 160, 160, 0};
        sb.d[ns++] = SmallDesc{OUT_meta, rWI4,         relWIb + 4 * 160, bmI,  N_META, 160, 160, 160, 0};
        sb.d[ns++] = SmallDesc{OUT_meta, rWO4,         relWOb + 4 * 160, bmO,  N_META, 160, 160, 160, 0};
        sb.d[ns++] = SmallDesc{OUT_rel,  rWI4 + 25600, nullptr,          brI,  N_RELN, 160, 160, 160, 0};
        sb.d[ns++] = SmallDesc{OUT_rel,  rWO4 + 25600, nullptr,          brO,  N_RELN, 160, 160, 160, 0};
        sb.d[ns++] = SmallDesc{OUT_rel,  relWS + (size_t)4 * 25600, relWSb + 4 * 160,
                               hR4, N_RELN, 160, 160, 160, 0};
        sb.d[ns++] = SmallDesc{OUT_rel,  WI5,          entWIb + 5 * 160, ar5I, N_RELN, 160, 160, 160, 0};
        sb.d[ns++] = SmallDesc{OUT_rel,  WO5,          entWOb + 5 * 160, ar5O, N_RELN, 160, 160, 160, 0};
        sb.d[ns++] = SmallDesc{OUT_tim,  WI5 + 51200,  nullptr,          at5I, N_TIME,  80, 160, 160, 0};
        sb.d[ns++] = SmallDesc{OUT_tim,  WO5 + 51200,  nullptr,          at5O, N_TIME,  80, 160, 160, 0};
        sb.d[ns++] = SmallDesc{OUT_meta, rWI5,         relWIb + 5 * 160, bm5I, N_META, 160, 160, 160, 0};
        sb.d[ns++] = SmallDesc{OUT_meta, rWO5,         relWOb + 5 * 160, bm5O, N_META, 160, 160, 160, 0};
        sb.d[ns++] = SmallDesc{OUT_rel,  rWI5 + 25600, nullptr,          br5I, N_RELN, 160, 160, 160, 0};
        sb.d[ns++] = SmallDesc{OUT_rel,  rWO5 + 25600, nullptr,          br5O, N_RELN, 160, 160, 160, 0};
        sb.d[ns++] = SmallDesc{OUT_rel,  relWS + (size_t)5 * 25600, relWSb + 5 * 160,
                               hR5, N_RELN, 160, 160, 160, 0};
        stage_p1<<<dim3(800, ns + 1), 256, 0, stream>>>(sb, ns, OUT_ent, Ahg, Alg, 400000);

        // P2a: mean-head big GEMMs + rel mean agg -> hR4
        AggRelA ar4{rowptrR, packR, bmI, bmO, brI, brO, hR4, 0};
        stage_p2<<<dim3(400, 4), 256, 0, stream>>>(Ahg, Alg, N_ENT, bigmf(4, B5v), ar4);
        // P3a: ent mean agg -> B5v
        agg_ent_csr<<<3125, 256, 0, stream>>>(
            rowptrE, packE, arI, arO, AI, AO, atI, atO, B5v, 0);
        // P2b: logstd-head big GEMMs (no rel role)
        AggRelA arNull{};
        stage_p2<<<dim3(313, 3), 256, 0, stream>>>(Ahg, Alg, N_ENT, bigmf(5, B1v), arNull);
        // P3b: ent logstd agg + sample -> B5v ; rel logstd agg + sample -> zR
        heads_p3b<<<dim3(3125, 2), 256, 0, stream>>>(
            rowptrE, packE, ar5I, ar5O, AI, AO, at5I, at5O, B1v, B5v, noiseE, B5v,
            rowptrR, packR, bm5I, bm5O, br5I, br5O, hR5, hR4, noiseR, zR);
    }

    // ---- decoder (layers 2,3) ----
    stage(2, B5v, zR, OUT_tim, OUT_meta, B1v, tim_o1, rel_o1, meta_o1, 1);
    stage(3, B1v, rel_o1, tim_o1, meta_o1, OUT_ento, OUT_timo, OUT_relo, OUT_metao, 0);
}